// Round 7
// baseline (872.755 us; speedup 1.0000x reference)
//
#include <hip/hip_runtime.h>

// VonMisesNet: B=128, V=128, F=40, H=256, L=32, FL=1024, OUT=1
#define Bsz 128
#define Vn  128
#define Fdim 40
#define Hdim 256
#define Lnum 32
#define FLdim 1024
#define LN_EPS 1e-5f

typedef unsigned short u16;
typedef __attribute__((ext_vector_type(8))) short short8;
typedef __attribute__((ext_vector_type(4))) float f32x4;

__device__ __forceinline__ u16 f2bf(float f) {
    unsigned u = __float_as_uint(f);
    u += 0x7fff + ((u >> 16) & 1);          // round-to-nearest-even
    return (u16)(u >> 16);
}
__device__ __forceinline__ float bf2f(u16 s) {
    return __uint_as_float((unsigned)s << 16);
}

__device__ __forceinline__ void split4(const f32x4& f, ushort4& h4, ushort4& l4) {
    u16 h0 = f2bf(f[0]), h1 = f2bf(f[1]), h2 = f2bf(f[2]), h3 = f2bf(f[3]);
    h4.x = h0; h4.y = h1; h4.z = h2; h4.w = h3;
    l4.x = f2bf(f[0] - bf2f(h0));
    l4.y = f2bf(f[1] - bf2f(h1));
    l4.z = f2bf(f[2] - bf2f(h2));
    l4.w = f2bf(f[3] - bf2f(h3));
}

// ---------------- rowsum: n[m] = sum_j G[m,j]; invdeg = 1/(n + (n==0)) ----------------
__global__ __launch_bounds__(256) void rowsum_kernel(const float* __restrict__ G,
                                                     float* __restrict__ nrow,
                                                     float* __restrict__ invdeg) {
    int row = blockIdx.x * 4 + (threadIdx.x >> 6);
    int lane = threadIdx.x & 63;
    const float* g = G + (size_t)row * Vn;
    float s = g[lane] + g[lane + 64];
    #pragma unroll
    for (int off = 32; off; off >>= 1) s += __shfl_down(s, off);
    if (lane == 0) {
        nrow[row] = s;
        invdeg[row] = 1.0f / (s + (s == 0.0f ? 1.0f : 0.0f));
    }
}

// ---------------- Gbf[b][i][j] = bf16(G + diag(n)) (exact: 0/1/int) ----------------
__global__ __launch_bounds__(256) void gbf_kernel(const float* __restrict__ G,
                                                  const float* __restrict__ nrow,
                                                  u16* __restrict__ gbf) {
    int gid = blockIdx.x * 256 + threadIdx.x;      // handles 8 j's
    int j8 = gid & 15;
    int m  = gid >> 4;                             // b*128 + i
    int i  = m & 127;
    const float* src = G + (size_t)m * Vn + j8 * 8;
    float4 g0 = *(const float4*)src;
    float4 g1 = *(const float4*)(src + 4);
    float nb = nrow[m];
    float ge[8] = {g0.x, g0.y, g0.z, g0.w, g1.x, g1.y, g1.z, g1.w};
    u16 us[8];
    #pragma unroll
    for (int e = 0; e < 8; ++e) {
        float val = ge[e] + ((j8 * 8 + e) == i ? nb : 0.0f);
        us[e] = f2bf(val);
    }
    uint4 pack;
    pack.x = (unsigned)us[0] | ((unsigned)us[1] << 16);
    pack.y = (unsigned)us[2] | ((unsigned)us[3] << 16);
    pack.z = (unsigned)us[4] | ((unsigned)us[5] << 16);
    pack.w = (unsigned)us[6] | ((unsigned)us[7] << 16);
    *(uint4*)(gbf + (size_t)m * Vn + j8 * 8) = pack;
}

// ------------- transpose+split: src[K][N] f32 -> hi/lo[N][K] bf16 (per blockIdx.z mat) -------------
__global__ __launch_bounds__(256) void tsplit_kernel(const float* __restrict__ src,
                                                     u16* __restrict__ hi, u16* __restrict__ lo,
                                                     int N, int K) {
    __shared__ float tl[64][65];
    size_t mat = (size_t)blockIdx.z * K * N;
    int k0 = blockIdx.x * 64, n0 = blockIdx.y * 64;
    int t = threadIdx.x, c = t & 63, r4 = t >> 6;
    #pragma unroll
    for (int i = 0; i < 16; ++i) {
        int r = i * 4 + r4;
        tl[r][c] = src[mat + (size_t)(k0 + r) * N + n0 + c];
    }
    __syncthreads();
    #pragma unroll
    for (int i = 0; i < 16; ++i) {
        int nr = i * 4 + r4;
        float val = tl[c][nr];
        u16 h = f2bf(val);
        size_t idx = mat + (size_t)(n0 + nr) * K + k0 + c;
        hi[idx] = h;
        lo[idx] = f2bf(val - bf2f(h));
    }
}

// ---------------- feat: v = x@W_feat + b_feat (fp32 master only) ----------------
__global__ __launch_bounds__(256) void feat_kernel(const float* __restrict__ x,
                                                   const float* __restrict__ Wf,
                                                   const float* __restrict__ bf,
                                                   float* __restrict__ v) {
    __shared__ float xs[Fdim];
    int row = blockIdx.x;
    int h = threadIdx.x;
    if (h < Fdim) xs[h] = x[(size_t)row * Fdim + h];
    __syncthreads();
    float acc = bf[h];
    #pragma unroll 8
    for (int f = 0; f < Fdim; ++f) acc += xs[f] * Wf[f * Hdim + h];
    v[(size_t)row * Hdim + h] = acc;
}

// ================= ALL 32 LAYERS in one kernel: block = one batch, v in registers =========
// 512 threads = 8 waves (2 wr x 4 wc). LDS 128KB region X:
//   phase A (GEMM1): AsH[128 i][256 k]=64K @0, AsL 64K @65536   (v split, rows 512B)
//   phase B (GEMM2): VPH[256 d][128 j]=64K @0, VPL 64K @65536   (vp split, rows 256B)
// G fragments live in 32 VGPRs for all layers; W fragments read direct from global (L2-hot).
// v_regs mapping: (d = dd*128 + wr*64 + mi*16 + lq*4 + r, i = wc*32 + ni*16 + lr)
__global__ __launch_bounds__(512, 2) void layers_all(float* __restrict__ v_io,
                                                     const u16* __restrict__ wthi_all,
                                                     const u16* __restrict__ wtlo_all,
                                                     const float* __restrict__ b_all,
                                                     const u16* __restrict__ gbf,
                                                     const float* __restrict__ invdeg) {
    extern __shared__ char smem[];
    char* AsH = smem;
    char* AsL = smem + 65536;
    char* VPH = smem;
    char* VPL = smem + 65536;

    const int tid = threadIdx.x, l = tid & 63, w = tid >> 6;
    const int wr = w >> 2, wc = w & 3;               // 2 x 4 wave grid
    const int b = blockIdx.x;
    const int lr = l & 15, lq = l >> 4, lkb = lq * 16;
    const int sw = (lr & 7) << 4;                    // row&7 == lr&7 for every tile here

    // ---- G fragments: B-operand of GEMM2, rows i = wc*32+ni*16+lr (persist all layers) ----
    const char* gb = (const char*)gbf + (size_t)b * 32768;
    short8 gfr[2][4];
    #pragma unroll
    for (int ni = 0; ni < 2; ++ni)
        #pragma unroll
        for (int kc = 0; kc < 4; ++kc)
            gfr[ni][kc] = *(const short8*)(gb + (size_t)(wc * 32 + ni * 16 + lr) * 256 + kc * 64 + lkb);

    float invd[2];
    #pragma unroll
    for (int ni = 0; ni < 2; ++ni) invd[ni] = invdeg[b * 128 + wc * 32 + ni * 16 + lr];

    // ---- load v into registers ----
    float* vb = v_io + (size_t)b * 128 * 256;
    f32x4 vreg[2][4][2];
    #pragma unroll
    for (int dd = 0; dd < 2; ++dd)
        #pragma unroll
        for (int mi = 0; mi < 4; ++mi)
            #pragma unroll
            for (int ni = 0; ni < 2; ++ni) {
                int i = wc * 32 + ni * 16 + lr;
                int d0 = dd * 128 + wr * 64 + mi * 16 + lq * 4;
                vreg[dd][mi][ni] = *(const f32x4*)(vb + (size_t)i * 256 + d0);
            }

    for (int layer = 0; layer < Lnum; ++layer) {
        const char* wh = (const char*)wthi_all + (size_t)layer * 131072;
        const char* wl_ = (const char*)wtlo_all + (size_t)layer * 131072;
        const float* bias = b_all + layer * 256;
        float bv[2][2];
        #pragma unroll
        for (int dd = 0; dd < 2; ++dd)
            #pragma unroll
            for (int ni = 0; ni < 2; ++ni)
                bv[dd][ni] = bias[dd * 128 + wc * 32 + ni * 16 + lr];

        __syncthreads();                 // previous layer's VP reads complete
        // ---- step 1: v regs -> As split [i][k=d], rows 512B, swizzled ----
        #pragma unroll
        for (int dd = 0; dd < 2; ++dd)
            #pragma unroll
            for (int mi = 0; mi < 4; ++mi)
                #pragma unroll
                for (int ni = 0; ni < 2; ++ni) {
                    int i = wc * 32 + ni * 16 + lr;
                    int d0 = dd * 128 + wr * 64 + mi * 16 + lq * 4;
                    ushort4 h4, l4;
                    split4(vreg[dd][mi][ni], h4, l4);
                    int off = (i * 512 + d0 * 2) ^ sw;
                    *(ushort4*)(AsH + off) = h4;
                    *(ushort4*)(AsL + off) = l4;
                }
        __syncthreads();

        // ---- GEMM1: vp[j][d] = v @ W, split-bf16 (3 products), K=256 ----
        f32x4 z = {0.f, 0.f, 0.f, 0.f};
        f32x4 acc1[2][4][2];
        #pragma unroll
        for (int dd = 0; dd < 2; ++dd)
            #pragma unroll
            for (int mi = 0; mi < 4; ++mi) { acc1[dd][mi][0] = z; acc1[dd][mi][1] = z; }

        #pragma unroll 2
        for (int kc = 0; kc < 8; ++kc) {
            // issue global W loads first (latency hidden by the LDS A reads below)
            short8 Bh[2][2], Bl[2][2];
            #pragma unroll
            for (int dd = 0; dd < 2; ++dd)
                #pragma unroll
                for (int ni = 0; ni < 2; ++ni) {
                    size_t woff = (size_t)(dd * 128 + wc * 32 + ni * 16 + lr) * 512 + kc * 64 + lkb;
                    Bh[dd][ni] = *(const short8*)(wh + woff);
                    Bl[dd][ni] = *(const short8*)(wl_ + woff);
                }
            short8 Ah[4], Al[4];
            #pragma unroll
            for (int mi = 0; mi < 4; ++mi) {
                int off = ((wr * 64 + mi * 16 + lr) * 512 + kc * 64 + lkb) ^ sw;
                Ah[mi] = *(const short8*)(AsH + off);
                Al[mi] = *(const short8*)(AsL + off);
            }
            #pragma unroll
            for (int dd = 0; dd < 2; ++dd)
                #pragma unroll
                for (int mi = 0; mi < 4; ++mi)
                    #pragma unroll
                    for (int ni = 0; ni < 2; ++ni) {
                        acc1[dd][mi][ni] = __builtin_amdgcn_mfma_f32_16x16x32_bf16(
                            Ah[mi], Bh[dd][ni], acc1[dd][mi][ni], 0, 0, 0);
                        acc1[dd][mi][ni] = __builtin_amdgcn_mfma_f32_16x16x32_bf16(
                            Al[mi], Bh[dd][ni], acc1[dd][mi][ni], 0, 0, 0);
                        acc1[dd][mi][ni] = __builtin_amdgcn_mfma_f32_16x16x32_bf16(
                            Ah[mi], Bl[dd][ni], acc1[dd][mi][ni], 0, 0, 0);
                    }
        }
        __syncthreads();                 // As dead

        // ---- epi 1: vp = acc1 + bias -> split -> VP [d][j], rows 256B, swizzled ----
        // acc1 mapping: j = wr*64+mi*16+lq*4+r, d = dd*128+wc*32+ni*16+lr
        #pragma unroll
        for (int dd = 0; dd < 2; ++dd)
            #pragma unroll
            for (int mi = 0; mi < 4; ++mi)
                #pragma unroll
                for (int ni = 0; ni < 2; ++ni) {
                    int d = dd * 128 + wc * 32 + ni * 16 + lr;
                    int j0 = wr * 64 + mi * 16 + lq * 4;
                    f32x4 t = acc1[dd][mi][ni];
                    t[0] += bv[dd][ni]; t[1] += bv[dd][ni];
                    t[2] += bv[dd][ni]; t[3] += bv[dd][ni];
                    ushort4 h4, l4;
                    split4(t, h4, l4);
                    int off = (d * 256 + j0 * 2) ^ sw;
                    *(ushort4*)(VPH + off) = h4;
                    *(ushort4*)(VPL + off) = l4;
                }
        __syncthreads();

        // ---- GEMM2: C2[d][i] = sum_j vp[d][j] * Gp[i][j] (hi seg then lo seg) ----
        f32x4 acc2[2][4][2];
        #pragma unroll
        for (int dd = 0; dd < 2; ++dd)
            #pragma unroll
            for (int mi = 0; mi < 4; ++mi) { acc2[dd][mi][0] = z; acc2[dd][mi][1] = z; }

        #pragma unroll
        for (int s = 0; s < 2; ++s) {
            const char* Aseg = s ? VPL : VPH;
            #pragma unroll
            for (int kc = 0; kc < 4; ++kc) {
                short8 Af[2][4];
                #pragma unroll
                for (int dd = 0; dd < 2; ++dd)
                    #pragma unroll
                    for (int mi = 0; mi < 4; ++mi) {
                        int off = ((dd * 128 + wr * 64 + mi * 16 + lr) * 256 + kc * 64 + lkb) ^ sw;
                        Af[dd][mi] = *(const short8*)(Aseg + off);
                    }
                #pragma unroll
                for (int dd = 0; dd < 2; ++dd)
                    #pragma unroll
                    for (int mi = 0; mi < 4; ++mi)
                        #pragma unroll
                        for (int ni = 0; ni < 2; ++ni)
                            acc2[dd][mi][ni] = __builtin_amdgcn_mfma_f32_16x16x32_bf16(
                                Af[dd][mi], gfr[ni][kc], acc2[dd][mi][ni], 0, 0, 0);
            }
        }

        // ---- epi 2 (registers): v += relu(C2 * invdeg) ----
        #pragma unroll
        for (int dd = 0; dd < 2; ++dd)
            #pragma unroll
            for (int mi = 0; mi < 4; ++mi)
                #pragma unroll
                for (int ni = 0; ni < 2; ++ni)
                    #pragma unroll
                    for (int r = 0; r < 4; ++r)
                        vreg[dd][mi][ni][r] += fmaxf(acc2[dd][mi][ni][r] * invd[ni], 0.0f);
    }

    // ---- store v back ----
    #pragma unroll
    for (int dd = 0; dd < 2; ++dd)
        #pragma unroll
        for (int mi = 0; mi < 4; ++mi)
            #pragma unroll
            for (int ni = 0; ni < 2; ++ni) {
                int i = wc * 32 + ni * 16 + lr;
                int d0 = dd * 128 + wr * 64 + mi * 16 + lq * 4;
                *(f32x4*)(vb + (size_t)i * 256 + d0) = vreg[dd][mi][ni];
            }
}

// ---------------- LayerNorm: read v fp32, write split h ----------------
__global__ __launch_bounds__(256) void ln_kernel(const float* __restrict__ v,
                                                 const float* __restrict__ g,
                                                 const float* __restrict__ beta,
                                                 u16* __restrict__ hhi,
                                                 u16* __restrict__ hlo) {
    __shared__ float sbuf[4];
    int row = blockIdx.x;
    int t = threadIdx.x;
    float x = v[(size_t)row * Hdim + t];
    float s = x;
    #pragma unroll
    for (int off = 32; off; off >>= 1) s += __shfl_down(s, off);
    int wid = t >> 6, lane = t & 63;
    if (lane == 0) sbuf[wid] = s;
    __syncthreads();
    float mu = (sbuf[0] + sbuf[1] + sbuf[2] + sbuf[3]) * (1.0f / Hdim);
    __syncthreads();
    float d = x - mu;
    float sq = d * d;
    #pragma unroll
    for (int off = 32; off; off >>= 1) sq += __shfl_down(sq, off);
    if (lane == 0) sbuf[wid] = sq;
    __syncthreads();
    float var = (sbuf[0] + sbuf[1] + sbuf[2] + sbuf[3]) * (1.0f / Hdim);
    float h = d * (1.0f / sqrtf(var + LN_EPS)) * g[t] + beta[t];
    size_t idx = (size_t)row * Hdim + t;
    u16 hb = f2bf(h);
    hhi[idx] = hb;
    hlo[idx] = f2bf(h - bf2f(hb));
}

// ---------------- fused final GEMM (direct staging + swizzle): part[m][nb] ----------------
__global__ __launch_bounds__(256) void gemm_fin_mfma(const u16* __restrict__ hhi,
                                                     const u16* __restrict__ hlo,
                                                     const u16* __restrict__ wfhi,
                                                     const u16* __restrict__ wflo,
                                                     const float* __restrict__ bfin,
                                                     const float* __restrict__ wout,
                                                     float* __restrict__ part) {
    __shared__ char smem[24576];
    char* As = smem;                 // 16384 (rows 128B)
    char* Bs = smem + 16384;         // 8192  (rows 128B)
    int tid = threadIdx.x, l = tid & 63, w = tid >> 6, wr = w >> 1, wc = w & 1;
    int m0 = blockIdx.x * 128, n0 = blockIdx.y * 64;
    const int lr = l & 15, lq = l >> 4, lkb = lq * 16;
    const int sw = (lr & 7) << 4;
    const char* segA[3] = {(const char*)hhi, (const char*)hlo, (const char*)hhi};
    const char* segB[3] = {(const char*)wfhi, (const char*)wfhi, (const char*)wflo};
    f32x4 z = {0.f, 0.f, 0.f, 0.f};
    f32x4 acc[4][2];
    #pragma unroll
    for (int mi = 0; mi < 4; ++mi) { acc[mi][0] = z; acc[mi][1] = z; }

    for (int q = 0; q < 12; ++q) {
        const char* A = segA[q >> 2] + (size_t)m0 * 512 + (q & 3) * 128;
        const char* B = segB[q >> 2] + (size_t)n0 * 512 + (q & 3) * 128;
        #pragma unroll
        for (int u = 0; u < 4; ++u) {
            int off = (u * 256 + tid) * 16;
            int row = off >> 7;
            *(uint4*)(As + (off ^ ((row & 7) << 4))) =
                *(const uint4*)(A + (size_t)row * 512 + (off & 127));
        }
        #pragma unroll
        for (int u = 0; u < 2; ++u) {
            int off = (u * 256 + tid) * 16;
            int row = off >> 7;
            *(uint4*)(Bs + (off ^ ((row & 7) << 4))) =
                *(const uint4*)(B + (size_t)row * 512 + (off & 127));
        }
        __syncthreads();
        #pragma unroll
        for (int kk = 0; kk < 2; ++kk) {
            short8 a[4], b2[2];
            #pragma unroll
            for (int mi = 0; mi < 4; ++mi)
                a[mi] = *(const short8*)(As + (((wr * 64 + mi * 16 + lr) * 128 + kk * 64 + lkb) ^ sw));
            #pragma unroll
            for (int ni = 0; ni < 2; ++ni)
                b2[ni] = *(const short8*)(Bs + (((wc * 32 + ni * 16 + lr) * 128 + kk * 64 + lkb) ^ sw));
            #pragma unroll
            for (int mi = 0; mi < 4; ++mi)
                #pragma unroll
                for (int ni = 0; ni < 2; ++ni)
                    acc[mi][ni] = __builtin_amdgcn_mfma_f32_16x16x32_bf16(a[mi], b2[ni],
                                                                         acc[mi][ni], 0, 0, 0);
        }
        __syncthreads();
    }
    float rs[4][4];
    #pragma unroll
    for (int mi = 0; mi < 4; ++mi)
        #pragma unroll
        for (int r = 0; r < 4; ++r) rs[mi][r] = 0.0f;
    #pragma unroll
    for (int ni = 0; ni < 2; ++ni) {
        int n = n0 + wc * 32 + ni * 16 + lr;
        float bvv = bfin[n], wo = wout[n];
        #pragma unroll
        for (int mi = 0; mi < 4; ++mi)
            #pragma unroll
            for (int r = 0; r < 4; ++r)
                rs[mi][r] += fmaxf(acc[mi][ni][r] + bvv, 0.0f) * wo;
    }
    float* red = (float*)smem;          // [128][33] floats; loop ended with barrier
    #pragma unroll
    for (int mi = 0; mi < 4; ++mi)
        #pragma unroll
        for (int r = 0; r < 4; ++r) {
            int row = wr * 64 + mi * 16 + lq * 4 + r;
            red[row * 33 + wc * 16 + lr] = rs[mi][r];
        }
    __syncthreads();
    if (tid < 128) {
        float s = 0.0f;
        #pragma unroll
        for (int c = 0; c < 32; ++c) s += red[tid * 33 + c];
        part[(size_t)(m0 + tid) * 16 + blockIdx.y] = s;
    }
}

// ---------------- final reduce ----------------
__global__ __launch_bounds__(256) void final_kernel(const float* __restrict__ part,
                                                    const float* __restrict__ bo,
                                                    float* __restrict__ out) {
    int i = blockIdx.x * 256 + threadIdx.x;
    float s = bo[0];
    #pragma unroll
    for (int t = 0; t < 16; ++t) s += part[(size_t)i * 16 + t];
    out[i] = s;
}

extern "C" void kernel_launch(void* const* d_in, const int* in_sizes, int n_in,
                              void* d_out, int out_size, void* d_ws, size_t ws_size,
                              hipStream_t stream) {
    const float* x        = (const float*)d_in[0];
    const float* G        = (const float*)d_in[1];
    const float* W_feat   = (const float*)d_in[2];
    const float* b_feat   = (const float*)d_in[3];
    const float* W_layers = (const float*)d_in[4];
    const float* b_layers = (const float*)d_in[5];
    const float* ln_g     = (const float*)d_in[6];
    const float* ln_b     = (const float*)d_in[7];
    const float* W_fin    = (const float*)d_in[8];
    const float* b_fin    = (const float*)d_in[9];
    const float* W_out    = (const float*)d_in[10];
    const float* b_out    = (const float*)d_in[11];
    float* out = (float*)d_out;

    const int M = Bsz * Vn;                          // 16384
    char* ws = (char*)d_ws;
    float* v0     = (float*)ws;                      ws += (size_t)M * Hdim * 4;     // 16 MB
    u16*   gbf    = (u16*)ws;                        ws += (size_t)Bsz * Vn * Vn * 2;   // 4 MB
    u16*   wthi   = (u16*)ws;                        ws += (size_t)Lnum * Hdim * Hdim * 2; // 4 MB
    u16*   wtlo   = (u16*)ws;                        ws += (size_t)Lnum * Hdim * Hdim * 2; // 4 MB
    u16*   wfhi   = (u16*)ws;                        ws += (size_t)FLdim * Hdim * 2;  // 0.5 MB
    u16*   wflo   = (u16*)ws;                        ws += (size_t)FLdim * Hdim * 2;  // 0.5 MB
    float* nrow   = (float*)ws;                      ws += (size_t)M * 4;
    float* invdeg = (float*)ws;                      ws += (size_t)M * 4;
    float* part   = (float*)ws;                      ws += (size_t)M * 16 * 4;        // 1 MB
    u16*   hh     = (u16*)ws;                        ws += (size_t)M * Hdim * 2;      // 8 MB
    u16*   hl     = (u16*)ws;                        ws += (size_t)M * Hdim * 2;      // 8 MB

    hipFuncSetAttribute((const void*)layers_all,
                        hipFuncAttributeMaxDynamicSharedMemorySize, 131072);

    rowsum_kernel<<<M / 4, 256, 0, stream>>>(G, nrow, invdeg);
    gbf_kernel<<<(Bsz * Vn * 16) / 256, 256, 0, stream>>>(G, nrow, gbf);
    tsplit_kernel<<<dim3(4, 4, Lnum), 256, 0, stream>>>(W_layers, wthi, wtlo, Hdim, Hdim);
    tsplit_kernel<<<dim3(4, 16, 1), 256, 0, stream>>>(W_fin, wfhi, wflo, FLdim, Hdim);
    feat_kernel<<<M, 256, 0, stream>>>(x, W_feat, b_feat, v0);

    layers_all<<<Bsz, 512, 131072, stream>>>(v0, wthi, wtlo, b_layers, gbf, invdeg);

    ln_kernel<<<M, 256, 0, stream>>>(v0, ln_g, ln_b, hh, hl);
    gemm_fin_mfma<<<dim3(M / 128, FLdim / 64), 256, 0, stream>>>(
        hh, hl, wfhi, wflo, b_fin, W_out, part);
    final_kernel<<<M / 256, 256, 0, stream>>>(part, b_out, out);
}